// Round 1
// 236.141 us; speedup vs baseline: 1.1750x; 1.1750x over previous
//
#include <hip/hip_runtime.h>

// vol[n,d,h,w] = sum_c L[n,c,h,w] * R[n,c,h,w-d], 0 if w<d
// N=4, C=128, H=160, W=320, D=48, fp32 in/out.
//
// MFMA formulation: per (n,h) this is a banded GEMM G[w,j] = sum_c L[c,w]*R[c,j]
// (d = w - j, keep 0 <= d < 48). 1280 blocks = (n,h) x 2 w-halves, 640 threads =
// 10 waves; wave wt owns output w-tile [wb+16wt, wb+16wt+16).
//  - A (L) fragments loaded DIRECTLY from global to regs (no LDS), packed f32->f16.
//  - B (R) staged once in LDS as h2 channel-pairs, [208 rows j][68 cols c2] with
//    XOR column swizzle; B-frag = one ds_read_b128.
//  - 16 x mfma_f32_16x16x32_f16 per wave (4 q-tiles x 4 k-steps), band-masked
//    epilogue transposed through LDS so global stores are float4 along w.

#define NN 4
#define CC 128
#define HH 160
#define WW 320
#define DD 48
#define HWs (HH * WW)
#define WB 160     // w extent per block
#define RROWS 208  // staged R rows: j in [wb-48, wb+160)
#define RPITCH 68  // h2 per row: 64 c-pairs + 4 pad (row stride 272 B)
#define RTASKS 3328  // 64 c2 x 52 float4-positions

typedef _Float16 h2 __attribute__((ext_vector_type(2)));
typedef _Float16 f16x8 __attribute__((ext_vector_type(8)));
typedef float f32x4 __attribute__((ext_vector_type(4)));
typedef __fp16 h2raw __attribute__((ext_vector_type(2)));

__device__ __forceinline__ h2 pack2(float a, float b) {
  union { h2raw r; h2 h; } u;
  u.r = __builtin_amdgcn_cvt_pkrtz(a, b);  // v_cvt_pkrtz_f16_f32
  return u.h;
}

__global__ __launch_bounds__(640)
void corr_kernel(const float* __restrict__ L, const float* __restrict__ R,
                 float* __restrict__ out) {
  // 56,576 B; also reused as the epilogue transpose buffer (10 x 48x20 f32).
  __shared__ __align__(16) h2 Rh[RROWS][RPITCH];

  const int tid = threadIdx.x;
  const int wt  = tid >> 6;   // wave id == w-tile 0..9
  const int ln  = tid & 63;
  const int i16 = ln & 15;    // frag m/n index
  const int g   = ln >> 4;    // k-group 0..3

  const int bid = blockIdx.x;
  const int wsplit = bid & 1;
  const int row_nh = bid >> 1;
  const int n = row_nh / HH;
  const int h = row_nh - n * HH;
  const int wb = wsplit * WB;

  const size_t base = (size_t)n * CC * HWs + (size_t)h * WW;
  const float* Rbase = R + base;                      // + c*HWs + col
  const float* Lbase = L + base + wb + 16 * wt + i16; // + c*HWs

  // ---- issue R staging loads (burst; zero-fill j<0, 4-aligned so all-or-none)
  union F4 { float4 f; float a[4]; };
  F4 ra[6], rc[6];
#pragma unroll
  for (int it = 0; it < 6; ++it) {
    int t = tid + it * 640;
    ra[it].f = make_float4(0.f, 0.f, 0.f, 0.f);
    rc[it].f = make_float4(0.f, 0.f, 0.f, 0.f);
    if (t < RTASKS) {
      int c2 = t / 52, v = t - 52 * c2;
      int col = wb - 48 + 4 * v;
      if (col >= 0) {
        const float* p = Rbase + (size_t)(2 * c2) * HWs + col;
        ra[it].f = *(const float4*)p;
        rc[it].f = *(const float4*)(p + HWs);
      }
    }
  }

  // ---- issue L fragment loads: lane -> L[c = 32ks+8g+e][w0+i16]
  // (16 consecutive lanes read 64 B aligned segments; no LDS round-trip)
  float lv[32];
#pragma unroll
  for (int ks = 0; ks < 4; ++ks)
#pragma unroll
    for (int e = 0; e < 8; ++e)
      lv[ks * 8 + e] = Lbase[(size_t)(32 * ks + 8 * g + e) * HWs];

  // ---- write R to LDS: h2 = (c,c+1) pair; column XOR-swizzled so the
  // row-scattered b32 writes spread across banks (row stride 272 B ~= 4 words)
#pragma unroll
  for (int it = 0; it < 6; ++it) {
    int t = tid + it * 640;
    if (t < RTASKS) {
      int c2 = t / 52, v = t - 52 * c2;
      int colp = c2 ^ (4 * (v & 7));  // (4v+i)>>2 == v for i<4
#pragma unroll
      for (int i = 0; i < 4; ++i)
        Rh[4 * v + i][colp] = pack2(ra[it].a[i], rc[it].a[i]);
    }
  }

  // ---- pack L frags: element e of frag ks <-> channel c = 32ks + 8g + e
  union AU { f16x8 v; h2 h[4]; };
  AU A[4];
#pragma unroll
  for (int ks = 0; ks < 4; ++ks)
#pragma unroll
    for (int j = 0; j < 4; ++j)
      A[ks].h[j] = pack2(lv[ks * 8 + 2 * j], lv[ks * 8 + 2 * j + 1]);

  __syncthreads();

  // ---- MFMA: 4 q-tiles (j-base = wb-48+16(wt+q)) x 4 k-steps
  f32x4 acc[4] = {};
#pragma unroll
  for (int q = 0; q < 4; ++q) {
    const int row = 16 * (wt + q) + i16;       // LDS j row (B's n = i16)
    const int swz = 4 * ((row >> 2) & 7);
    union BU { float4 f; f16x8 v; } B;
#pragma unroll
    for (int ks = 0; ks < 4; ++ks) {
      B.f = *(const float4*)&Rh[row][(16 * ks + 4 * g) ^ swz];
      acc[q] = __builtin_amdgcn_mfma_f32_16x16x32_f16(A[ks].v, B.v, acc[q], 0, 0, 0);
    }
  }

  __syncthreads();  // all B-frag reads done; Rh reused as epilogue buffer

  // ---- epilogue: lane holds D[m=4g+r][n=i16] -> w = w0+4g+r, d = 48-16q+4g+r-i16.
  // Band masks are a disjoint exact cover of d in [0,48). Transpose through LDS
  // ([48 d][20-pad w] f32 per wave) so global stores are float4 along w.
  float* Ep = ((float*)&Rh[0][0]) + wt * (DD * 20);
#pragma unroll
  for (int q = 0; q < 4; ++q)
#pragma unroll
    for (int r = 0; r < 4; ++r) {
      int d = 48 - 16 * q + 4 * g + r - i16;
      if (d >= 0 && d < DD) Ep[d * 20 + 4 * g + r] = acc[q][r];
    }
  // own-wave write->read; compiler inserts the lgkmcnt wait

  const int l4 = ln & 3;
  const int dr = ln >> 2;  // 0..15
  float* outp = out + (size_t)n * DD * HWs + (size_t)h * WW + wb + 16 * wt + 4 * l4;
#pragma unroll
  for (int rr = 0; rr < 3; ++rr) {
    int d = 16 * rr + dr;
    float4 val = *(const float4*)&Ep[d * 20 + 4 * l4];
    *(float4*)&outp[(size_t)d * HWs] = val;
  }
}

extern "C" void kernel_launch(void* const* d_in, const int* in_sizes, int n_in,
                              void* d_out, int out_size, void* d_ws, size_t ws_size,
                              hipStream_t stream) {
  const float* L = (const float*)d_in[0];
  const float* R = (const float*)d_in[1];
  float* out = (float*)d_out;
  corr_kernel<<<dim3(2 * NN * HH), dim3(640), 0, stream>>>(L, R, out);
}